// Round 4
// baseline (592.792 us; speedup 1.0000x reference)
//
#include <hip/hip_runtime.h>
#include <cstdint>
#include <cstddef>
#include <cmath>

// ---------------------------------------------------------------------------
// DotProductAttention: out = softmax_causal((x@Q/32) @ (x@K)^T) @ (x@V)
//   B=4, S=4096, D=1024, fp32 in/out, bf16 MFMA compute.
// R4 changes vs R3 (588 us):
//   - gemm_bt K-loop rewritten as a 3-deep software pipeline on
//     global_load_lds: tile k+2 issued at iter k, explicit
//     s_waitcnt vmcnt(8) + raw s_barrier instead of __syncthreads.
//     Loads complete ~2 iterations before use -> latency hidden even at
//     1-3 blocks/CU. BK=32, 3 LDS buffer pairs = 48 KB (3 blocks/CU).
//   - tail iters use vmcnt(4)/vmcnt(0) (no dummy loads)
// Structure otherwise identical to R3 (fused Q+K proj, TRI scores grid,
// CK-limited PV, softmax zero-pads rows to 128).
// Workspace map (224 MB):
//   [0,64)   QKx bf16 [B*S][2048]  (Qx=+0, Kx=+1024, ld 2048)
//   [64,96)  Vxt bf16 [B][D][S]
//   [96,224) Sb bf16 [B][S][S]  -- early-phase reuse (all dead before Sb):
//       Vtmp@96 (32M), XB@128 (32M), WTqk@160 (4M), WTv@164 (2M)
// ---------------------------------------------------------------------------

typedef unsigned short u16;
typedef __bf16  bf16x8 __attribute__((ext_vector_type(8)));
typedef float   f32x4  __attribute__((ext_vector_type(4)));
typedef unsigned short u16x4 __attribute__((ext_vector_type(4)));

typedef __attribute__((address_space(1))) void gvoid;
typedef __attribute__((address_space(3))) void lvoid;

// s_waitcnt imm encoding (gfx9): vmcnt[3:0]=bits0-3, expcnt=bits4-6,
// lgkmcnt=bits8-11. 0xF70 = no-wait expcnt/lgkmcnt, vmcnt in low bits.
#define WAIT_VM(n) __builtin_amdgcn_s_waitcnt(0xF70 | (n))

__device__ __forceinline__ u16 f2bf(float f) {
  union { float f; unsigned u; } v; v.f = f;
  unsigned u = v.u;
  u += 0x7FFFu + ((u >> 16) & 1u);   // round-to-nearest-even
  return (u16)(u >> 16);
}
__device__ __forceinline__ float bf2f(u16 h) {
  union { unsigned u; float f; } v; v.u = ((unsigned)h) << 16;
  return v.f;
}
__device__ __forceinline__ void async16(const void* g, void* l) {
  __builtin_amdgcn_global_load_lds((gvoid*)(void*)g, (lvoid*)l, 16, 0, 0);
}

// --------------------------- elementwise convert ---------------------------
__global__ void __launch_bounds__(256) cvt_f32_bf16(const float4* __restrict__ in,
                                                    u16* __restrict__ out, int n4) {
  int i = blockIdx.x * 256 + threadIdx.x;
  if (i >= n4) return;
  float4 v = in[i];
  u16x4 o = { f2bf(v.x), f2bf(v.y), f2bf(v.z), f2bf(v.w) };
  *(u16x4*)(out + 4 * (size_t)i) = o;
}

// ------------------------------- transpose ---------------------------------
__device__ __forceinline__ u16 to_bfs(float v, float s) { return f2bf(v * s); }
__device__ __forceinline__ u16 to_bfs(u16 v, float)     { return v; }

template <typename TIN>
__global__ void __launch_bounds__(256) transpose_to_bf16(
    const TIN* __restrict__ in, u16* __restrict__ out,
    int rows, int cols, long inStride, long outStride, float scale) {
  __shared__ u16 t[64][68];                 // stride 136B -> 2-way alias (free)
  int rt = blockIdx.x * 64, ct = blockIdx.y * 64;
  long ib = (long)blockIdx.z * inStride, ob = (long)blockIdx.z * outStride;
  int tx = threadIdx.x & 63, ty = threadIdx.x >> 6;
#pragma unroll
  for (int r = ty; r < 64; r += 4)
    t[r][tx] = to_bfs(in[ib + (long)(rt + r) * cols + ct + tx], scale);
  __syncthreads();
#pragma unroll
  for (int r = ty; r < 64; r += 4)
    out[ob + (long)(ct + r) * rows + rt + tx] = t[tx][r];
}

// ------------------------------- GEMM core ---------------------------------
// C[m][n] = alpha * sum_k A[m][k] * Bt[n][k]; A,Bt bf16 row-major.
// 128x128 tile, BK=32, 256 threads = 4 waves (2x2), 4x4 16x16x32 MFMAs/wave.
// 3-deep global_load_lds pipeline: per wave 4 loads/tile outstanding;
// issue tile i+2, then vmcnt(8) guarantees tile i's loads are in LDS.
// TRI: blockIdx.x is a compacted lower-triangular index (causal scores).
// CK:  limit k-reduction to (mt+1)*128 (causal PV); mt reversed for balance.
template <bool OUTF32, bool TRI, bool CK>
__global__ void __launch_bounds__(256) gemm_bt(
    const u16* __restrict__ A, const u16* __restrict__ Bt, void* __restrict__ C,
    int K, int lda, int ldb, int ldc,
    long aStride, long bStride, long cStride, float alpha) {
  int mt, nt;
  if (TRI) {
    const int bid = blockIdx.x;
    int m = (int)((sqrtf(8.0f * (float)bid + 1.0f) - 1.0f) * 0.5f);
    while ((m + 1) * (m + 2) / 2 <= bid) ++m;
    while (m * (m + 1) / 2 > bid) --m;
    mt = m; nt = bid - m * (m + 1) / 2;
  } else {
    mt = CK ? (int)(gridDim.x - 1 - blockIdx.x) : (int)blockIdx.x;
    nt = blockIdx.y;
  }
  const int bz = blockIdx.z;
  const int tid = threadIdx.x, wv = tid >> 6, ln = tid & 63;
  const u16* Ag = A + (long)bz * aStride + (long)(mt * 128) * lda;
  const u16* Bg = Bt + (long)bz * bStride + (long)(nt * 128) * ldb;

  // 3 buffers x (128x32 bf16 = 8 KB) for each of A,B = 48 KB total
  __shared__ __align__(16) __bf16 As[3][128 * 32];
  __shared__ __align__(16) __bf16 Bs[3][128 * 32];

  f32x4 acc[4][4];
#pragma unroll
  for (int i = 0; i < 4; ++i)
#pragma unroll
    for (int j = 0; j < 4; ++j)
#pragma unroll
      for (int r = 0; r < 4; ++r) acc[i][j][r] = 0.f;

  const int kend = CK ? (((mt + 1) * 128 < K) ? (mt + 1) * 128 : K) : K;
  const int nk = kend >> 5;                 // # BK=32 tiles, always >= 4 here
  const int mrow = (wv & 1) * 64, nrow = (wv >> 1) * 64;
  const int lr = ln & 15, quad = ln >> 4;

  // per-thread staging addresses (row/col within the 128x32 tile)
  const int chunk0 = wv * 64 + ln;                 // 0..255
  const int chunk1 = (wv + 4) * 64 + ln;           // 256..511
  const int row0s = chunk0 >> 2, c80 = (chunk0 & 3) << 3;
  const int row1s = chunk1 >> 2, c81 = (chunk1 & 3) << 3;
  const long aOff0 = (long)row0s * lda + c80, aOff1 = (long)row1s * lda + c81;
  const long bOff0 = (long)row0s * ldb + c80, bOff1 = (long)row1s * ldb + c81;
  const int ldsOff0 = wv * 512, ldsOff1 = (wv + 4) * 512;  // elements

#define ISSUE_TILE(t, p)                                            \
  do {                                                              \
    const long ko = (long)(t) << 5;                                 \
    async16(Ag + ko + aOff0, &As[p][ldsOff0]);                      \
    async16(Bg + ko + bOff0, &Bs[p][ldsOff0]);                      \
    async16(Ag + ko + aOff1, &As[p][ldsOff1]);                      \
    async16(Bg + ko + bOff1, &Bs[p][ldsOff1]);                      \
  } while (0)

  ISSUE_TILE(0, 0);
  ISSUE_TILE(1, 1);

  int cb = 0, ib = 2;
  for (int i = 0; i < nk; ++i) {
    if (i + 2 < nk) { ISSUE_TILE(i + 2, ib); WAIT_VM(8); }
    else if (i + 1 < nk) { WAIT_VM(4); }
    else { WAIT_VM(0); }
    __builtin_amdgcn_s_barrier();     // all waves' tile-i loads visible

    bf16x8 af[4], bfr[4];
#pragma unroll
    for (int u = 0; u < 4; ++u)
      af[u] = *(const bf16x8*)&As[cb][(mrow + u * 16 + lr) * 32 + quad * 8];
#pragma unroll
    for (int j = 0; j < 4; ++j)
      bfr[j] = *(const bf16x8*)&Bs[cb][(nrow + j * 16 + lr) * 32 + quad * 8];
#pragma unroll
    for (int u = 0; u < 4; ++u)
#pragma unroll
      for (int j = 0; j < 4; ++j)
        acc[u][j] = __builtin_amdgcn_mfma_f32_16x16x32_bf16(af[u], bfr[j], acc[u][j], 0, 0, 0);

    __builtin_amdgcn_s_barrier();     // buf cb free before iter i+1 refills it
    cb = (cb == 2) ? 0 : cb + 1;
    ib = (ib == 2) ? 0 : ib + 1;
  }
#undef ISSUE_TILE

  // epilogue: C/D layout col=lane&15, row=(lane>>4)*4+reg  [verified m89/m91]
  const long cbase = (long)bz * cStride;
#pragma unroll
  for (int i = 0; i < 4; ++i) {
    int row0 = mt * 128 + mrow + i * 16 + quad * 4;
#pragma unroll
    for (int j = 0; j < 4; ++j) {
      int col = nt * 128 + nrow + j * 16 + lr;
#pragma unroll
      for (int r = 0; r < 4; ++r) {
        float v = acc[i][j][r] * alpha;
        long idx = cbase + (long)(row0 + r) * ldc + col;
        if (OUTF32) ((float*)C)[idx] = v;
        else        ((u16*)C)[idx]  = f2bf(v);
      }
    }
  }
}

// ------------------------------ row softmax --------------------------------
__global__ void __launch_bounds__(256) softmax_rows(u16* __restrict__ Sb,
                                                    long bStride, int S) {
  const int row = blockIdx.x;
  u16* p = Sb + (long)blockIdx.y * bStride + (long)row * S;
  const int L = row + 1;
  const int Lpad = (L + 127) & ~127;
  const int tid = threadIdx.x, ln = tid & 63, wv = tid >> 6;
  __shared__ float red[8];

  float vals[16];
  float lmax = -3.4e38f;
#pragma unroll
  for (int k = 0; k < 16; ++k) {
    int j = tid + k * 256;
    if (j < L) { float v = bf2f(p[j]); vals[k] = v; lmax = fmaxf(lmax, v); }
  }
#pragma unroll
  for (int o = 32; o > 0; o >>= 1) lmax = fmaxf(lmax, __shfl_down(lmax, o));
  if (ln == 0) red[wv] = lmax;
  __syncthreads();
  float m = fmaxf(fmaxf(red[0], red[1]), fmaxf(red[2], red[3]));

  float lsum = 0.f;
#pragma unroll
  for (int k = 0; k < 16; ++k) {
    int j = tid + k * 256;
    if (j < L) { float e = __expf(vals[k] - m); vals[k] = e; lsum += e; }
  }
#pragma unroll
  for (int o = 32; o > 0; o >>= 1) lsum += __shfl_down(lsum, o);
  __syncthreads();
  if (ln == 0) red[wv] = lsum;
  __syncthreads();
  float inv = 1.f / (red[0] + red[1] + red[2] + red[3]);
#pragma unroll
  for (int k = 0; k < 16; ++k) {
    int j = tid + k * 256;
    if (j < L) p[j] = f2bf(vals[k] * inv);
  }
  for (int j = L + tid; j < Lpad; j += 256) p[j] = 0;
}

// ------------------------------- launcher ----------------------------------
extern "C" void kernel_launch(void* const* d_in, const int* in_sizes, int n_in,
                              void* d_out, int out_size, void* d_ws, size_t ws_size,
                              hipStream_t stream) {
  const float* x = (const float*)d_in[0];
  const float* Q = (const float*)d_in[1];
  const float* K = (const float*)d_in[2];
  const float* V = (const float*)d_in[3];
  float* out = (float*)d_out;

  constexpr int  Bb = 4, S = 4096, D = 1024;
  constexpr long MB = 1024 * 1024;
  if (ws_size < (size_t)(224 * MB)) return;

  char* ws = (char*)d_ws;
  u16* QKx  = (u16*)(ws);             // [B*S][2048]  Qx=+0, Kx=+1024
  u16* Vxt  = (u16*)(ws + 64 * MB);   // [B][D][S]
  u16* Sb   = (u16*)(ws + 96 * MB);   // [B][S][S]
  u16* Vtmp = (u16*)(ws + 96 * MB);   // [B][S][D]   (dead before Sb written)
  u16* XB   = (u16*)(ws + 128 * MB);  // x bf16      (dead before Sb written)
  u16* WTqk = (u16*)(ws + 160 * MB);  // [2048][1024]
  u16* WTv  = (u16*)(ws + 164 * MB);  // [1024][1024]

  const long SD = (long)S * D, SS = (long)S * S;

  // 1. x -> bf16
  cvt_f32_bf16<<<dim3((Bb * S * D / 4) / 256), 256, 0, stream>>>(
      (const float4*)x, XB, Bb * S * D / 4);

  // 2. weight transposes (fp32 [k][n] -> bf16 [n][k]); 1/32 folded into Qt
  transpose_to_bf16<float><<<dim3(16, 16, 1), 256, 0, stream>>>(
      Q, WTqk, 1024, 1024, 0, 0, 0.03125f);
  transpose_to_bf16<float><<<dim3(16, 16, 1), 256, 0, stream>>>(
      K, WTqk + 1024 * 1024, 1024, 1024, 0, 0, 1.0f);
  transpose_to_bf16<float><<<dim3(16, 16, 1), 256, 0, stream>>>(
      V, WTv, 1024, 1024, 0, 0, 1.0f);

  // 3a. fused Q,K projection -> QKx [B*S][2048]
  gemm_bt<false, false, false><<<dim3(128, 16, 1), 256, 0, stream>>>(
      XB, WTqk, QKx, 1024, 1024, 1024, 2048, 0, 0, 0, 1.0f);
  // 3b. V projection -> Vtmp
  gemm_bt<false, false, false><<<dim3(128, 8, 1), 256, 0, stream>>>(
      XB, WTv, Vtmp, 1024, 1024, 1024, 1024, 0, 0, 0, 1.0f);

  // 4. Vtmp [b][s][d] -> Vxt [b][d][s]
  transpose_to_bf16<u16><<<dim3(64, 16, Bb), 256, 0, stream>>>(
      Vtmp, Vxt, S, D, SD, SD, 1.0f);

  // 5. causal scores: Sb = Qx @ Kx^T, compacted triangular grid (528/batch)
  //    QKx batch stride is S*2048 = 2*SD (interleaved layout!)
  gemm_bt<false, true, false><<<dim3(528, 1, Bb), 256, 0, stream>>>(
      QKx, QKx + 1024, Sb, 1024, 2048, 2048, S, 2 * SD, 2 * SD, SS, 1.0f);

  // 6. row softmax in place (also zero-pads rows to 128 boundary)
  softmax_rows<<<dim3(S, Bb), 256, 0, stream>>>(Sb, SS, S);

  // 7. out = P @ Vxt^T (causal k-limit; longest blocks first)
  gemm_bt<true, false, true><<<dim3(32, 8, Bb), 256, 0, stream>>>(
      Sb, Vxt, out, S, S, S, D, SS, SD, SD, 1.0f);
}

// Round 5
// 534.006 us; speedup vs baseline: 1.1101x; 1.1101x over previous
//
#include <hip/hip_runtime.h>
#include <cstdint>
#include <cstddef>
#include <cmath>

// ---------------------------------------------------------------------------
// DotProductAttention: out = softmax_causal((x@Q/32) @ (x@K)^T) @ (x@V)
//   B=4, S=4096, D=1024, fp32 in/out, bf16 MFMA compute.
// R5 changes vs R4 (592 us) / R3 (588 us):
//   - GEMM block tile 256x128 (was 128x128), 256 threads = 4 waves (2x2),
//     wave tile 128x64, acc[8][4]. 2x MFMA per barrier, 0.75x staging
//     bytes/FLOP, 0.76x A+B cache traffic. LDS 48 KB -> 2 blocks/CU.
//   - XOR LDS swizzle: physical col8 = logical col8 ^ ((row>>1)&3).
//     Applied on the staging GLOBAL address (per-lane, so the wave-uniform
//     LDS-dest rule of global_load_lds is preserved) and on ds_read.
//     Read pattern becomes exact 2-way bank alias (free, m136).
//   - back to simple __syncthreads 2-panel BK=64 loop (R4's explicit
//     vmcnt pipeline was neutral -> dropped).
//   - softmax pads rows to 256 boundary (PV M-tile granularity).
//   - TRI grid mixed granularity: mt in 256-row units, nt in 128-col units;
//     blocks per mt = 2mt+2, cumulative C(m)=m(m+1), 272 blocks/batch.
// Workspace map (224 MB):
//   [0,64)   QKx bf16 [B*S][2048]  (Qx=+0, Kx=+1024, ld 2048)
//   [64,96)  Vxt bf16 [B][D][S]
//   [96,224) Sb bf16 [B][S][S]  -- early-phase reuse (all dead before Sb):
//       Vtmp@96 (32M), XB@128 (32M), WTqk@160 (4M), WTv@164 (2M)
// ---------------------------------------------------------------------------

typedef unsigned short u16;
typedef __bf16  bf16x8 __attribute__((ext_vector_type(8)));
typedef float   f32x4  __attribute__((ext_vector_type(4)));
typedef unsigned short u16x4 __attribute__((ext_vector_type(4)));

typedef __attribute__((address_space(1))) void gvoid;
typedef __attribute__((address_space(3))) void lvoid;

__device__ __forceinline__ u16 f2bf(float f) {
  union { float f; unsigned u; } v; v.f = f;
  unsigned u = v.u;
  u += 0x7FFFu + ((u >> 16) & 1u);   // round-to-nearest-even
  return (u16)(u >> 16);
}
__device__ __forceinline__ float bf2f(u16 h) {
  union { unsigned u; float f; } v; v.u = ((unsigned)h) << 16;
  return v.f;
}
__device__ __forceinline__ void async16(const void* g, void* l) {
  __builtin_amdgcn_global_load_lds((gvoid*)(void*)g, (lvoid*)l, 16, 0, 0);
}

// --------------------------- elementwise convert ---------------------------
__global__ void __launch_bounds__(256) cvt_f32_bf16(const float4* __restrict__ in,
                                                    u16* __restrict__ out, int n4) {
  int i = blockIdx.x * 256 + threadIdx.x;
  if (i >= n4) return;
  float4 v = in[i];
  u16x4 o = { f2bf(v.x), f2bf(v.y), f2bf(v.z), f2bf(v.w) };
  *(u16x4*)(out + 4 * (size_t)i) = o;
}

// ------------------------------- transpose ---------------------------------
__device__ __forceinline__ u16 to_bfs(float v, float s) { return f2bf(v * s); }
__device__ __forceinline__ u16 to_bfs(u16 v, float)     { return v; }

template <typename TIN>
__global__ void __launch_bounds__(256) transpose_to_bf16(
    const TIN* __restrict__ in, u16* __restrict__ out,
    int rows, int cols, long inStride, long outStride, float scale) {
  __shared__ u16 t[64][68];                 // stride 136B -> 2-way alias (free)
  int rt = blockIdx.x * 64, ct = blockIdx.y * 64;
  long ib = (long)blockIdx.z * inStride, ob = (long)blockIdx.z * outStride;
  int tx = threadIdx.x & 63, ty = threadIdx.x >> 6;
#pragma unroll
  for (int r = ty; r < 64; r += 4)
    t[r][tx] = to_bfs(in[ib + (long)(rt + r) * cols + ct + tx], scale);
  __syncthreads();
#pragma unroll
  for (int r = ty; r < 64; r += 4)
    out[ob + (long)(ct + r) * rows + rt + tx] = t[tx][r];
}

// ------------------------------- GEMM core ---------------------------------
// C[m][n] = alpha * sum_k A[m][k] * Bt[n][k]; A,Bt bf16 row-major.
// Block tile 256(M) x 128(N), BK=64 as two BK=32 LDS panels.
// 256 threads = 4 waves in 2x2; wave tile 128x64; 8x4 16x16x32 MFMAs/panel.
// TRI: blockIdx.x compacted causal grid (mt: 256-row units, nt: 128-col).
// CK:  k-reduction limited to (mt+1)*256 (causal PV); mt reversed.
template <bool OUTF32, bool TRI, bool CK>
__global__ void __launch_bounds__(256, 2) gemm_bt(
    const u16* __restrict__ A, const u16* __restrict__ Bt, void* __restrict__ C,
    int K, int lda, int ldb, int ldc,
    long aStride, long bStride, long cStride, float alpha) {
  int mt, nt;
  if (TRI) {
    const int bid = blockIdx.x;           // C(m) = m*(m+1); 2m+2 blocks per m
    int m = (int)((sqrtf(4.0f * (float)bid + 1.0f) - 1.0f) * 0.5f);
    while ((m + 1) * (m + 2) <= bid) ++m;
    while (m * (m + 1) > bid) --m;
    mt = m; nt = bid - m * (m + 1);
  } else {
    mt = CK ? (int)(gridDim.x - 1 - blockIdx.x) : (int)blockIdx.x;
    nt = blockIdx.y;
  }
  const int bz = blockIdx.z;
  const int tid = threadIdx.x, wv = tid >> 6, ln = tid & 63;
  const u16* Ag = A + (long)bz * aStride + (long)(mt * 256) * lda;
  const u16* Bg = Bt + (long)bz * bStride + (long)(nt * 128) * ldb;

  __shared__ __align__(16) __bf16 As[2][256 * 32];   // 32 KB
  __shared__ __align__(16) __bf16 Bs[2][128 * 32];   // 16 KB

  f32x4 acc[8][4];
#pragma unroll
  for (int i = 0; i < 8; ++i)
#pragma unroll
    for (int j = 0; j < 4; ++j)
#pragma unroll
      for (int r = 0; r < 4; ++r) acc[i][j][r] = 0.f;

  const int kend = CK ? (((mt + 1) * 256 < K) ? (mt + 1) * 256 : K) : K;
  const int wm = wv & 1, wn = wv >> 1;
  const int mrow = wm * 128, nrow = wn * 64;
  const int lr = ln & 15, quad = ln >> 4;

  // staging: A-tile 1024 chunks of 16B, B-tile 512 chunks; 6 per thread.
  // chunk c -> row=c>>2, logical col8 idx=c&3; swizzled GLOBAL col =
  // (c8i ^ ((row>>1)&3))*8 so that LDS slot (row,c8i) holds logical
  // column (c8i ^ swz(row)).
  long aOff[4]; int aLds[4];
#pragma unroll
  for (int q = 0; q < 4; ++q) {
    int c = q * 256 + tid, row = c >> 2, c8i = c & 3;
    aOff[q] = (long)row * lda + ((c8i ^ ((row >> 1) & 3)) << 3);
    aLds[q] = c * 8;                       // elements
  }
  long bOff[2]; int bLds[2];
#pragma unroll
  for (int q = 0; q < 2; ++q) {
    int c = q * 256 + tid, row = c >> 2, c8i = c & 3;
    bOff[q] = (long)row * ldb + ((c8i ^ ((row >> 1) & 3)) << 3);
    bLds[q] = c * 8;
  }
  // read-side swizzle: row = (multiple of 64) + u*16 + lr ->
  // (row>>1)&3 == (lr>>1)&3, lane-constant across all fragments.
  const int swq = (quad ^ ((lr >> 1) & 3)) << 3;

  for (int k0 = 0; k0 < kend; k0 += 64) {
#pragma unroll
    for (int p = 0; p < 2; ++p) {
      const long kk = k0 + p * 32;
#pragma unroll
      for (int q = 0; q < 4; ++q)
        async16(Ag + kk + aOff[q], (char*)As[p] + aLds[q] * 2);
#pragma unroll
      for (int q = 0; q < 2; ++q)
        async16(Bg + kk + bOff[q], (char*)Bs[p] + bLds[q] * 2);
    }
    __syncthreads();   // drains vmcnt before barrier
#pragma unroll
    for (int p = 0; p < 2; ++p) {
      bf16x8 af[8], bfr[4];
#pragma unroll
      for (int u = 0; u < 8; ++u)
        af[u] = *(const bf16x8*)&As[p][(mrow + u * 16 + lr) * 32 + swq];
#pragma unroll
      for (int j = 0; j < 4; ++j)
        bfr[j] = *(const bf16x8*)&Bs[p][(nrow + j * 16 + lr) * 32 + swq];
#pragma unroll
      for (int u = 0; u < 8; ++u)
#pragma unroll
        for (int j = 0; j < 4; ++j)
          acc[u][j] = __builtin_amdgcn_mfma_f32_16x16x32_bf16(af[u], bfr[j], acc[u][j], 0, 0, 0);
    }
    __syncthreads();   // protect LDS before next refill
  }

  // epilogue: C/D layout col=lane&15, row=(lane>>4)*4+reg  [verified m89/m91]
  const long cb = (long)bz * cStride;
#pragma unroll
  for (int i = 0; i < 8; ++i) {
    int row0 = mt * 256 + mrow + i * 16 + quad * 4;
#pragma unroll
    for (int j = 0; j < 4; ++j) {
      int col = nt * 128 + nrow + j * 16 + lr;
#pragma unroll
      for (int r = 0; r < 4; ++r) {
        float v = acc[i][j][r] * alpha;
        long idx = cb + (long)(row0 + r) * ldc + col;
        if (OUTF32) ((float*)C)[idx] = v;
        else        ((u16*)C)[idx]  = f2bf(v);
      }
    }
  }
}

// ------------------------------ row softmax --------------------------------
// One block per (row, batch). Pads [L, ceil256(L)) with zeros so the PV GEMM
// (256-row M-tiles, kend=(mt+1)*256) reads no garbage.
__global__ void __launch_bounds__(256) softmax_rows(u16* __restrict__ Sb,
                                                    long bStride, int S) {
  const int row = blockIdx.x;
  u16* p = Sb + (long)blockIdx.y * bStride + (long)row * S;
  const int L = row + 1;
  const int Lpad = (L + 255) & ~255;
  const int tid = threadIdx.x, ln = tid & 63, wv = tid >> 6;
  __shared__ float red[8];

  float vals[16];
  float lmax = -3.4e38f;
#pragma unroll
  for (int k = 0; k < 16; ++k) {
    int j = tid + k * 256;
    if (j < L) { float v = bf2f(p[j]); vals[k] = v; lmax = fmaxf(lmax, v); }
  }
#pragma unroll
  for (int o = 32; o > 0; o >>= 1) lmax = fmaxf(lmax, __shfl_down(lmax, o));
  if (ln == 0) red[wv] = lmax;
  __syncthreads();
  float m = fmaxf(fmaxf(red[0], red[1]), fmaxf(red[2], red[3]));

  float lsum = 0.f;
#pragma unroll
  for (int k = 0; k < 16; ++k) {
    int j = tid + k * 256;
    if (j < L) { float e = __expf(vals[k] - m); vals[k] = e; lsum += e; }
  }
#pragma unroll
  for (int o = 32; o > 0; o >>= 1) lsum += __shfl_down(lsum, o);
  __syncthreads();
  if (ln == 0) red[wv] = lsum;
  __syncthreads();
  float inv = 1.f / (red[0] + red[1] + red[2] + red[3]);
#pragma unroll
  for (int k = 0; k < 16; ++k) {
    int j = tid + k * 256;
    if (j < L) p[j] = f2bf(vals[k] * inv);
  }
  for (int j = L + tid; j < Lpad; j += 256) p[j] = 0;
}

// ------------------------------- launcher ----------------------------------
extern "C" void kernel_launch(void* const* d_in, const int* in_sizes, int n_in,
                              void* d_out, int out_size, void* d_ws, size_t ws_size,
                              hipStream_t stream) {
  const float* x = (const float*)d_in[0];
  const float* Q = (const float*)d_in[1];
  const float* K = (const float*)d_in[2];
  const float* V = (const float*)d_in[3];
  float* out = (float*)d_out;

  constexpr int  Bb = 4, S = 4096, D = 1024;
  constexpr long MB = 1024 * 1024;
  if (ws_size < (size_t)(224 * MB)) return;

  char* ws = (char*)d_ws;
  u16* QKx  = (u16*)(ws);             // [B*S][2048]  Qx=+0, Kx=+1024
  u16* Vxt  = (u16*)(ws + 64 * MB);   // [B][D][S]
  u16* Sb   = (u16*)(ws + 96 * MB);   // [B][S][S]
  u16* Vtmp = (u16*)(ws + 96 * MB);   // [B][S][D]   (dead before Sb written)
  u16* XB   = (u16*)(ws + 128 * MB);  // x bf16      (dead before Sb written)
  u16* WTqk = (u16*)(ws + 160 * MB);  // [2048][1024]
  u16* WTv  = (u16*)(ws + 164 * MB);  // [1024][1024]

  const long SD = (long)S * D, SS = (long)S * S;

  // 1. x -> bf16
  cvt_f32_bf16<<<dim3((Bb * S * D / 4) / 256), 256, 0, stream>>>(
      (const float4*)x, XB, Bb * S * D / 4);

  // 2. weight transposes (fp32 [k][n] -> bf16 [n][k]); 1/32 folded into Qt
  transpose_to_bf16<float><<<dim3(16, 16, 1), 256, 0, stream>>>(
      Q, WTqk, 1024, 1024, 0, 0, 0.03125f);
  transpose_to_bf16<float><<<dim3(16, 16, 1), 256, 0, stream>>>(
      K, WTqk + 1024 * 1024, 1024, 1024, 0, 0, 1.0f);
  transpose_to_bf16<float><<<dim3(16, 16, 1), 256, 0, stream>>>(
      V, WTv, 1024, 1024, 0, 0, 1.0f);

  // 3a. fused Q,K projection -> QKx [B*S][2048]   (M=16384 -> 64 m-tiles)
  gemm_bt<false, false, false><<<dim3(64, 16, 1), 256, 0, stream>>>(
      XB, WTqk, QKx, 1024, 1024, 1024, 2048, 0, 0, 0, 1.0f);
  // 3b. V projection -> Vtmp
  gemm_bt<false, false, false><<<dim3(64, 8, 1), 256, 0, stream>>>(
      XB, WTv, Vtmp, 1024, 1024, 1024, 1024, 0, 0, 0, 1.0f);

  // 4. Vtmp [b][s][d] -> Vxt [b][d][s]
  transpose_to_bf16<u16><<<dim3(64, 16, Bb), 256, 0, stream>>>(
      Vtmp, Vxt, S, D, SD, SD, 1.0f);

  // 5. causal scores: Sb = Qx @ Kx^T, TRI grid (16 m-tiles x up-to-32 n-tiles
  //    = 272 blocks/batch). QKx batch stride = S*2048 = 2*SD.
  gemm_bt<false, true, false><<<dim3(272, 1, Bb), 256, 0, stream>>>(
      QKx, QKx + 1024, Sb, 1024, 2048, 2048, S, 2 * SD, 2 * SD, SS, 1.0f);

  // 6. row softmax in place (zero-pads rows to 256 boundary)
  softmax_rows<<<dim3(S, Bb), 256, 0, stream>>>(Sb, SS, S);

  // 7. out = P @ Vxt^T (causal k-limit; longest blocks first)
  gemm_bt<true, false, true><<<dim3(16, 8, Bb), 256, 0, stream>>>(
      Sb, Vxt, out, S, S, S, D, SS, SD, SD, 1.0f);
}